// Round 9
// baseline (19.175 us; speedup 1.0000x reference)
//
#include <hip/hip_runtime.h>

#define MARGIN 1.0f
#define BATCH 256
#define N 512
#define THREADS 256
#define JCHUNK 256
#define CHUNKS 2                      // j-chunks per row
#define NBLOCKS (BATCH * CHUNKS)      // 512 blocks -> 2 blocks/CU

typedef unsigned long long ull;

#define TAG 0x5A5AULL
#define VAL48 0xFFFFFFFFFFFFULL
#define FIXED_SCALE 1048576.0f        // 2^20 fixed point; block sum < 2^40 -> fits 48 bits

// ws layout: ull acc[1024].
//   acc[b]       = TAG<<48 | llrintf(block_sum * 2^20)        (b = 0..511)
//   acc[512 + b] = TAG<<48 | (chunk==0 ? nrel*(N-nrel) : 0)
// Self-validating tagged words = data AND completion flag (see R8 notes):
// poison-safe, replay-idempotent (stale words bit-identical), >=1 finalizer
// guaranteed by each block acking its own stores (s_waitcnt vmcnt(0), no
// cache maintenance) before the check-once scan. No init, no reset.

__global__ __launch_bounds__(THREADS) void hinge_onepass(
    const float* __restrict__ scores,
    const int* __restrict__ rel,
    float* __restrict__ out,
    ull* __restrict__ acc)
{
    __shared__ float t[JCHUNK];
    __shared__ ull   wbal[THREADS / 64];
    __shared__ float wa[THREADS / 64];
    __shared__ int   wr[THREADS / 64];
    __shared__ ull   wsum[THREADS / 64];
    __shared__ ull   wpar[THREADS / 64];

    const int bid = blockIdx.x;
    const int row = bid >> 1;                 // bid / CHUNKS
    const int chunk = bid & 1;
    const int tid = threadIdx.x;
    const int wave = tid >> 6;
    const int lane = tid & 63;

    const float* srow = scores + row * N;
    const int*  rrow = rel + row * N;

    // ---- Phase 1a: ballot the j-chunk's nonrel mask (for compaction) ----
    const int j = chunk * JCHUNK + tid;       // JCHUNK == THREADS
    const float sj = srow[j];
    const int jnonrel = (rrow[j] == 0);
    const ull bal = __ballot(jnonrel);
    if (lane == 0) wbal[wave] = bal;

    // i-side: each thread owns two candidate-i items spanning the full row.
    const float s0 = srow[tid];
    const float s1 = srow[tid + THREADS];
    const int r0 = rrow[tid] > 0;
    const int r1 = rrow[tid + THREADS] > 0;
    const float m0 = r0 ? (MARGIN - s0) : -1e30f;
    const float m1 = r1 ? (MARGIN - s1) : -1e30f;

    __syncthreads();

    // ---- Phase 1b: block-compact nonrel j's to t[0..nnr), pad rest -1e30 ----
    const ull b0 = wbal[0], b1 = wbal[1], b2 = wbal[2], b3 = wbal[3];
    const int c0 = __popcll(b0), c1 = __popcll(b1),
              c2 = __popcll(b2), c3 = __popcll(b3);
    const int nnr = c0 + c1 + c2 + c3;                      // nonrel in chunk
    int waveoff = 0;
    if (wave > 0) waveoff += c0;
    if (wave > 1) waveoff += c1;
    if (wave > 2) waveoff += c2;
    const ull lm = (1ull << lane) - 1ull;                   // lanes below me
    const int nr_pre = waveoff + __popcll(bal & lm);        // nonrel among tid'<tid
    // Bijective slot assignment: nonrel -> compacted front; rel -> pad tail.
    const int slot = jnonrel ? nr_pre : (nnr + (tid - nr_pre));
    t[slot] = jnonrel ? sj : -1e30f;
    __syncthreads();

    // ---- Phase 1c: hinge accumulation over compacted j list ----
    const int jlen = (nnr + 3) >> 2;          // float4 count (pad slots = -1e30)
    float acc0 = 0.f, acc1 = 0.f;
    const float4* tq = (const float4*)t;      // uniform addr -> ds_read_b128 broadcast
    #pragma unroll 4
    for (int q = 0; q < jlen; ++q) {
        const float4 v = tq[q];
        float x, y;
        x = m0 + v.x; y = m1 + v.x; acc0 += fmaxf(x, 0.f); acc1 += fmaxf(y, 0.f);
        x = m0 + v.y; y = m1 + v.y; acc0 += fmaxf(x, 0.f); acc1 += fmaxf(y, 0.f);
        x = m0 + v.z; y = m1 + v.z; acc0 += fmaxf(x, 0.f); acc1 += fmaxf(y, 0.f);
        x = m0 + v.w; y = m1 + v.w; acc0 += fmaxf(x, 0.f); acc1 += fmaxf(y, 0.f);
    }

    // Fixed-order block reduction (deterministic before quantization).
    float a = acc0 + acc1;
    int   c = r0 + r1;                         // i-side rel count, FULL row
    for (int off = 32; off > 0; off >>= 1) {
        a += __shfl_down(a, off, 64);
        c += __shfl_down(c, off, 64);
    }
    if (lane == 0) { wa[wave] = a; wr[wave] = c; }
    __syncthreads();

    if (tid == 0) {
        const float bsum = wa[0] + wa[1] + wa[2] + wa[3];
        const int   nrel = wr[0] + wr[1] + wr[2] + wr[3];
        const ull fixed = (ull)llrintf(bsum * FIXED_SCALE);      // < 2^48
        const ull pairs = (chunk == 0) ? (ull)(nrel * (N - nrel)) : 0ULL;
        __hip_atomic_store(&acc[bid], (TAG << 48) | fixed,
                           __ATOMIC_RELAXED, __HIP_MEMORY_SCOPE_AGENT);
        __hip_atomic_store(&acc[NBLOCKS + bid], (TAG << 48) | pairs,
                           __ATOMIC_RELAXED, __HIP_MEMORY_SCOPE_AGENT);
        // Ack OUR stores at the coherence point (no cache maintenance).
        asm volatile("s_waitcnt vmcnt(0)" ::: "memory");
    }
    __syncthreads();       // whole block ordered after wave 0's store-ack wait

    // ---- Phase 2: check-once (4 relaxed agent loads per thread) ----
    const ull e0 = __hip_atomic_load(&acc[tid],                 __ATOMIC_RELAXED, __HIP_MEMORY_SCOPE_AGENT);
    const ull e1 = __hip_atomic_load(&acc[tid + 256],           __ATOMIC_RELAXED, __HIP_MEMORY_SCOPE_AGENT);
    const ull e2 = __hip_atomic_load(&acc[NBLOCKS + tid],       __ATOMIC_RELAXED, __HIP_MEMORY_SCOPE_AGENT);
    const ull e3 = __hip_atomic_load(&acc[NBLOCKS + tid + 256], __ATOMIC_RELAXED, __HIP_MEMORY_SCOPE_AGENT);
    const int valid = ((e0 >> 48) == TAG) & ((e1 >> 48) == TAG) &
                      ((e2 >> 48) == TAG) & ((e3 >> 48) == TAG);

    if (__syncthreads_and(valid)) {
        // Finalize: order-free integer sums -> identical bits for any finalizer.
        ull sf = (e0 & VAL48) + (e1 & VAL48);
        ull pf = (e2 & VAL48) + (e3 & VAL48);
        for (int off = 32; off > 0; off >>= 1) {
            sf += __shfl_down(sf, off, 64);
            pf += __shfl_down(pf, off, 64);
        }
        if (lane == 0) { wsum[wave] = sf; wpar[wave] = pf; }
        __syncthreads();
        if (tid == 0) {
            const ull sumfixed = wsum[0] + wsum[1] + wsum[2] + wsum[3];
            const ull pairsum  = wpar[0] + wpar[1] + wpar[2] + wpar[3];
            const double total = (double)sumfixed * (1.0 / 1048576.0);
            out[0] = pairsum ? (float)(total / (double)pairsum) : 0.f;
        }
    }
}

extern "C" void kernel_launch(void* const* d_in, const int* in_sizes, int n_in,
                              void* d_out, int out_size, void* d_ws, size_t ws_size,
                              hipStream_t stream) {
    const float* scores = (const float*)d_in[0];
    const int* rel = (const int*)d_in[1];
    float* out = (float*)d_out;
    ull* acc = (ull*)d_ws;     // 1024 * 8 B

    hinge_onepass<<<NBLOCKS, THREADS, 0, stream>>>(scores, rel, out, acc);
}

// Round 10
// 12.368 us; speedup vs baseline: 1.5503x; 1.5503x over previous
//
#include <hip/hip_runtime.h>

#define MARGIN 1.0f
#define BATCH 256
#define N 512
#define THREADS 256
#define JCHUNK 64
#define CHUNKS (N / JCHUNK)          // 8 j-chunks per row
#define NBLOCKS (BATCH * CHUNKS)     // 2048 blocks -> 8 blocks/CU, full occupancy

typedef float f2 __attribute__((ext_vector_type(2)));

// R2 structure (best measured: 12.7 us), with the two per-thread accumulators
// fused into one float2 so the compiler can emit packed VOP3P f32 ops
// (v_pk_add_f32; elementwise max falls back to 2x v_max_f32 if no pk form).
// Numerically identical per component -> absmax 0.0 as R2.

__global__ __launch_bounds__(THREADS) void hinge_pairs(
    const float* __restrict__ scores,
    const int* __restrict__ rel,
    float* __restrict__ psum,   // [NBLOCKS]
    float* __restrict__ pcnt)   // [BATCH]
{
    __shared__ float t[JCHUNK];
    __shared__ float wa[THREADS / 64];
    __shared__ float wc[THREADS / 64];

    const int bid = blockIdx.x;
    const int row = bid >> 3;                 // bid / CHUNKS
    const int chunk = bid & (CHUNKS - 1);
    const int tid = threadIdx.x;

    const float* srow = scores + row * N;
    const int* rrow = rel + row * N;

    // Stage this block's j-chunk with sentinels (threads 0..63, coalesced):
    //   t[j] = s_j if j nonrel else -1e30  (=> relu(m_i + t[j]) == 0)
    if (tid < JCHUNK) {
        const int j = chunk * JCHUNK + tid;
        const float sj = srow[j];
        t[tid] = (rrow[j] == 0) ? sj : -1e30f;
    }

    // Each thread owns two candidate-i items (coalesced global loads).
    const float s0 = srow[tid];
    const float s1 = srow[tid + THREADS];
    const int r0 = rrow[tid] > 0;
    const int r1 = rrow[tid + THREADS] > 0;
    const f2 mm = { r0 ? (MARGIN - s0) : -1e30f,
                    r1 ? (MARGIN - s1) : -1e30f };

    __syncthreads();

    f2 acc = { 0.f, 0.f };
    const f2 zero = { 0.f, 0.f };
    const float4* tq = (const float4*)t;      // uniform addr -> ds_read_b128 broadcast
    #pragma unroll
    for (int q = 0; q < JCHUNK / 4; ++q) {
        const float4 v = tq[q];
        f2 d;
        d = mm + (f2){ v.x, v.x }; acc += __builtin_elementwise_max(d, zero);
        d = mm + (f2){ v.y, v.y }; acc += __builtin_elementwise_max(d, zero);
        d = mm + (f2){ v.z, v.z }; acc += __builtin_elementwise_max(d, zero);
        d = mm + (f2){ v.w, v.w }; acc += __builtin_elementwise_max(d, zero);
    }

    // Fixed-order block reduction (deterministic).
    float a = acc.x + acc.y;
    float c = (float)(r0 + r1);
    for (int off = 32; off > 0; off >>= 1) {
        a += __shfl_down(a, off, 64);
        c += __shfl_down(c, off, 64);
    }
    const int wave = tid >> 6;
    const int lane = tid & 63;
    if (lane == 0) { wa[wave] = a; wc[wave] = c; }
    __syncthreads();
    if (tid == 0) {
        psum[bid] = wa[0] + wa[1] + wa[2] + wa[3];
        if (chunk == 0) {
            const float nr = wc[0] + wc[1] + wc[2] + wc[3];
            pcnt[row] = nr * ((float)N - nr);  // num_rel * num_nonrel, exact in fp32
        }
    }
}

// Kernel 2: single block reduces 2048 partial sums + 256 pair counts, divides.
__global__ __launch_bounds__(THREADS) void hinge_finalize(
    const float* __restrict__ psum,
    const float* __restrict__ pcnt,
    float* __restrict__ out)
{
    __shared__ float wa[THREADS / 64];
    __shared__ float wc[THREADS / 64];
    const int tid = threadIdx.x;

    float a = 0.0f;
    #pragma unroll
    for (int k = 0; k < NBLOCKS / THREADS; ++k)   // 8 coalesced passes
        a += psum[tid + k * THREADS];
    float c = pcnt[tid];

    for (int off = 32; off > 0; off >>= 1) {
        a += __shfl_down(a, off, 64);
        c += __shfl_down(c, off, 64);
    }
    const int wave = tid >> 6;
    const int lane = tid & 63;
    if (lane == 0) { wa[wave] = a; wc[wave] = c; }
    __syncthreads();
    if (tid == 0) {
        const float total = wa[0] + wa[1] + wa[2] + wa[3];
        const float cnt = wc[0] + wc[1] + wc[2] + wc[3];
        out[0] = cnt > 0.0f ? total / cnt : 0.0f;
    }
}

extern "C" void kernel_launch(void* const* d_in, const int* in_sizes, int n_in,
                              void* d_out, int out_size, void* d_ws, size_t ws_size,
                              hipStream_t stream) {
    const float* scores = (const float*)d_in[0];
    const int* rel = (const int*)d_in[1];
    float* out = (float*)d_out;

    // Workspace: 2048 floats (per-block sums) + 256 floats (per-row pair counts).
    float* psum = (float*)d_ws;
    float* pcnt = psum + NBLOCKS;

    hinge_pairs<<<NBLOCKS, THREADS, 0, stream>>>(scores, rel, psum, pcnt);
    hinge_finalize<<<1, THREADS, 0, stream>>>(psum, pcnt, out);
}